// Round 3
// baseline (538.534 us; speedup 1.0000x reference)
//
#include <hip/hip_runtime.h>
#include <hip/hip_bf16.h>
#include <math.h>

#define D_MODEL 1024
#define D_STATE 16
#define D_CONV  4
#define D_INNER 2048
#define DT_RANK 64
#define B_SZ    2
#define SEQ     1024
#define ML      (B_SZ * SEQ)   // 2048 rows (b*L)

typedef unsigned short ushort_t;
typedef __attribute__((ext_vector_type(8))) short s8v;
typedef __attribute__((ext_vector_type(4))) float f4v;

__device__ __forceinline__ float softplus_f(float v) {
    return (v > 20.f) ? v : log1pf(__expf(v));
}

// ---------------------------------------------------------------------------
// Split f32 -> (hi, lo) bf16 pair, written in GEMM-tiled layout:
// tile (rt, kt) of [128 rows][32 k] is 4096 contiguous elements at
// (rt*ktiles + kt)*4096, row-major [r][k]. One thread converts 8 k-elements.
// ---------------------------------------------------------------------------
__global__ __launch_bounds__(256) void split_bf16_tiled(
    const float* __restrict__ A, ushort_t* __restrict__ H, ushort_t* __restrict__ L,
    int Kd, int ktlog, int total)
{
    int t = blockIdx.x * 256 + threadIdx.x;
    if (t >= total) return;
    int kslot = t & 3;
    int r  = (t >> 2) & 127;
    int tl = t >> 9;
    int kt = tl & ((1 << ktlog) - 1);
    int rt = tl >> ktlog;
    int row = rt * 128 + r;
    int col = (kt << 5) + kslot * 8;

    const float* src = &A[(size_t)row * Kd + col];
    float4 v0 = *reinterpret_cast<const float4*>(src);
    float4 v1 = *reinterpret_cast<const float4*>(src + 4);
    float f[8] = {v0.x, v0.y, v0.z, v0.w, v1.x, v1.y, v1.z, v1.w};
    s8v hv, lv;
#pragma unroll
    for (int j = 0; j < 8; ++j) {
        unsigned int ub = __float_as_uint(f[j]);
        unsigned int hb = (ub + 0x7fffu + ((ub >> 16) & 1u)) >> 16;   // RNE to bf16
        float hf = __uint_as_float(hb << 16);
        float g  = f[j] - hf;                                         // exact
        unsigned int ug = __float_as_uint(g);
        unsigned int lb = (ug + 0x7fffu + ((ug >> 16) & 1u)) >> 16;
        hv[j] = (short)hb;
        lv[j] = (short)lb;
    }
    *reinterpret_cast<s8v*>(&H[(size_t)t * 8]) = hv;
    *reinterpret_cast<s8v*>(&L[(size_t)t * 8]) = lv;
}

// ---------------------------------------------------------------------------
// Split-bf16 MFMA GEMM (m97 structure): C[m,n] = sum_k A[m,k]*W[n,k] (+R)
// A,W pre-split into hi/lo bf16 in tiled layout above. Block = BMx128,
// 4 waves (2x2), wave tile = (WTM*16) x 64, mfma_f32_16x16x32_bf16,
// 3-pass split accumulate. BK=32, single-buffered LDS, 2-barrier loop.
// ---------------------------------------------------------------------------
template <int WTM, bool RES>
__global__ __launch_bounds__(256) void gemm_mfma_split(
    const ushort_t* __restrict__ Ah, const ushort_t* __restrict__ Al,
    const ushort_t* __restrict__ Bh, const ushort_t* __restrict__ Bl,
    const float* __restrict__ Rres,
    float* __restrict__ C, int ldc, int K)
{
    constexpr int BM  = WTM * 32;
    constexpr int CPW = BM / 64;            // A-chunks (of 16 rows) per wave
    __shared__ short AhL[BM * 32], AlL[BM * 32];
    __shared__ short BhL[128 * 32], BlL[128 * 32];

    const int tid = threadIdx.x;
    const int l = tid & 63;
    const int w = tid >> 6;
    const int m0 = blockIdx.y * BM;
    const int n0 = blockIdx.x * 128;
    const int wm = (w >> 1) * (WTM * 16);
    const int wn = (w & 1) * 64;

    const int ktiles = K >> 5;
    size_t abase = (size_t)(m0 >> 7) * ktiles * 4096 + (size_t)(m0 & 127) * 32;
    size_t bbase = (size_t)(n0 >> 7) * ktiles * 4096;

    f4v acc[WTM][4] = {};

    for (int kt = 0; kt < ktiles; ++kt) {
        // ---- stage global -> LDS (linear, 16B per lane, wave-uniform base) ----
#pragma unroll
        for (int i = 0; i < CPW; ++i) {
            int ci = w * CPW + i;
            __builtin_amdgcn_global_load_lds(
                (const __attribute__((address_space(1))) unsigned int*)(Ah + abase + ci * 512 + l * 8),
                (__attribute__((address_space(3))) unsigned int*)&AhL[ci * 512], 16, 0, 0);
            __builtin_amdgcn_global_load_lds(
                (const __attribute__((address_space(1))) unsigned int*)(Al + abase + ci * 512 + l * 8),
                (__attribute__((address_space(3))) unsigned int*)&AlL[ci * 512], 16, 0, 0);
        }
#pragma unroll
        for (int i = 0; i < 2; ++i) {
            int ci = w * 2 + i;
            __builtin_amdgcn_global_load_lds(
                (const __attribute__((address_space(1))) unsigned int*)(Bh + bbase + ci * 512 + l * 8),
                (__attribute__((address_space(3))) unsigned int*)&BhL[ci * 512], 16, 0, 0);
            __builtin_amdgcn_global_load_lds(
                (const __attribute__((address_space(1))) unsigned int*)(Bl + bbase + ci * 512 + l * 8),
                (__attribute__((address_space(3))) unsigned int*)&BlL[ci * 512], 16, 0, 0);
        }
        asm volatile("s_waitcnt vmcnt(0)" ::: "memory");
        __syncthreads();

        // ---- fragment loads (ds_read_b128) ----
        s8v fah[WTM], fal[WTM], fbh[4], fbl[4];
        const int fo = (l & 15) * 32 + (l >> 4) * 8;   // row-in-tile*32 + k-offset
#pragma unroll
        for (int tr = 0; tr < WTM; ++tr) {
            fah[tr] = *reinterpret_cast<const s8v*>(&AhL[(wm + tr * 16) * 32 + fo]);
            fal[tr] = *reinterpret_cast<const s8v*>(&AlL[(wm + tr * 16) * 32 + fo]);
        }
#pragma unroll
        for (int tc = 0; tc < 4; ++tc) {
            fbh[tc] = *reinterpret_cast<const s8v*>(&BhL[(wn + tc * 16) * 32 + fo]);
            fbl[tc] = *reinterpret_cast<const s8v*>(&BlL[(wn + tc * 16) * 32 + fo]);
        }

        // ---- 3-pass split MFMA: Ah*Bh + Ah*Bl + Al*Bh ----
#pragma unroll
        for (int tr = 0; tr < WTM; ++tr)
#pragma unroll
            for (int tc = 0; tc < 4; ++tc) {
                f4v c = acc[tr][tc];
                c = __builtin_amdgcn_mfma_f32_16x16x32_bf16(fah[tr], fbh[tc], c, 0, 0, 0);
                c = __builtin_amdgcn_mfma_f32_16x16x32_bf16(fah[tr], fbl[tc], c, 0, 0, 0);
                c = __builtin_amdgcn_mfma_f32_16x16x32_bf16(fal[tr], fbh[tc], c, 0, 0, 0);
                acc[tr][tc] = c;
            }
        __syncthreads();
        abase += 4096;
        bbase += 4096;
    }

    // ---- epilogue: D layout col=lane&15, row=(lane>>4)*4+reg (m89-verified) ----
    const int mb = m0 + wm + ((l >> 4) << 2);
    const int nb = n0 + wn + (l & 15);
#pragma unroll
    for (int tr = 0; tr < WTM; ++tr)
#pragma unroll
        for (int tc = 0; tc < 4; ++tc)
#pragma unroll
            for (int r = 0; r < 4; ++r) {
                int m = mb + tr * 16 + r;
                int n = nb + tc * 16;
                float v = acc[tr][tc][r];
                if (RES) v += Rres[(size_t)m * ldc + n];
                C[(size_t)m * ldc + n] = v;
            }
}

// ---------------------------------------------------------------------------
// f32 GEMM (kept for dt_proj only): C = softplus(A@W^T + bias)
// ---------------------------------------------------------------------------
template <int BM, int BN, int TM, int TN, int ACT, bool BIAS>
__global__ __launch_bounds__(256) void gemm_tn(
    const float* __restrict__ A, int lda,
    const float* __restrict__ W, int ldw,
    const float* __restrict__ bias,
    float* __restrict__ C, int ldc,
    int K)
{
    constexpr int BK = 16;
    constexpr int LDA_S = BM + 4;
    constexpr int LDB_S = BN + 4;
    constexpr int RSUB = TM / 4;
    constexpr int CSUB = TN / 4;
    constexpr int NTX = BN / TN;
    constexpr int AF4 = BM * 4 / 256;
    constexpr int BF4 = BN * 4 / 256;
    static_assert((BM / TM) * (BN / TN) == 256, "256 threads");

    __shared__ float As[BK][LDA_S];
    __shared__ float Bs[BK][LDB_S];

    const int tid = threadIdx.x;
    const int tx = tid % NTX;
    const int ty = tid / NTX;
    const int m0 = blockIdx.y * BM;
    const int n0 = blockIdx.x * BN;

    float acc[TM][TN] = {};
    float4 pa[AF4], pb[BF4];

#pragma unroll
    for (int i = 0; i < AF4; ++i) {
        int f = tid + i * 256, row = f >> 2, kq = f & 3;
        pa[i] = *reinterpret_cast<const float4*>(&A[(size_t)(m0 + row) * lda + kq * 4]);
    }
#pragma unroll
    for (int i = 0; i < BF4; ++i) {
        int f = tid + i * 256, row = f >> 2, kq = f & 3;
        pb[i] = *reinterpret_cast<const float4*>(&W[(size_t)(n0 + row) * ldw + kq * 4]);
    }

    for (int k0 = 0; k0 < K; k0 += BK) {
#pragma unroll
        for (int i = 0; i < AF4; ++i) {
            int f = tid + i * 256, row = f >> 2, kq = f & 3;
            As[kq * 4 + 0][row] = pa[i].x; As[kq * 4 + 1][row] = pa[i].y;
            As[kq * 4 + 2][row] = pa[i].z; As[kq * 4 + 3][row] = pa[i].w;
        }
#pragma unroll
        for (int i = 0; i < BF4; ++i) {
            int f = tid + i * 256, row = f >> 2, kq = f & 3;
            Bs[kq * 4 + 0][row] = pb[i].x; Bs[kq * 4 + 1][row] = pb[i].y;
            Bs[kq * 4 + 2][row] = pb[i].z; Bs[kq * 4 + 3][row] = pb[i].w;
        }
        __syncthreads();

        if (k0 + BK < K) {
#pragma unroll
            for (int i = 0; i < AF4; ++i) {
                int f = tid + i * 256, row = f >> 2, kq = f & 3;
                pa[i] = *reinterpret_cast<const float4*>(&A[(size_t)(m0 + row) * lda + k0 + BK + kq * 4]);
            }
#pragma unroll
            for (int i = 0; i < BF4; ++i) {
                int f = tid + i * 256, row = f >> 2, kq = f & 3;
                pb[i] = *reinterpret_cast<const float4*>(&W[(size_t)(n0 + row) * ldw + k0 + BK + kq * 4]);
            }
        }

#pragma unroll
        for (int kk = 0; kk < BK; ++kk) {
            float a[TM], b[TN];
#pragma unroll
            for (int r = 0; r < RSUB; ++r) {
                float4 av = *reinterpret_cast<const float4*>(&As[kk][r * (BM / RSUB) + ty * 4]);
                a[r * 4 + 0] = av.x; a[r * 4 + 1] = av.y; a[r * 4 + 2] = av.z; a[r * 4 + 3] = av.w;
            }
#pragma unroll
            for (int c = 0; c < CSUB; ++c) {
                float4 bv = *reinterpret_cast<const float4*>(&Bs[kk][c * (BN / CSUB) + tx * 4]);
                b[c * 4 + 0] = bv.x; b[c * 4 + 1] = bv.y; b[c * 4 + 2] = bv.z; b[c * 4 + 3] = bv.w;
            }
#pragma unroll
            for (int i = 0; i < TM; ++i)
#pragma unroll
                for (int j = 0; j < TN; ++j)
                    acc[i][j] = fmaf(a[i], b[j], acc[i][j]);
        }
        __syncthreads();
    }

#pragma unroll
    for (int i = 0; i < TM; ++i) {
        int r = i >> 2, ii = i & 3;
        int m = m0 + r * (BM / RSUB) + ty * 4 + ii;
#pragma unroll
        for (int c = 0; c < CSUB; ++c) {
            int n = n0 + c * (BN / CSUB) + tx * 4;
            float v0 = acc[i][c * 4 + 0], v1 = acc[i][c * 4 + 1];
            float v2 = acc[i][c * 4 + 2], v3 = acc[i][c * 4 + 3];
            if (BIAS) {
                float4 b4 = *reinterpret_cast<const float4*>(&bias[n]);
                v0 += b4.x; v1 += b4.y; v2 += b4.z; v3 += b4.w;
            }
            if (ACT == 1) {
                v0 = softplus_f(v0); v1 = softplus_f(v1);
                v2 = softplus_f(v2); v3 = softplus_f(v3);
            }
            *reinterpret_cast<float4*>(&C[(size_t)m * ldc + n]) = make_float4(v0, v1, v2, v3);
        }
    }
}

// ---------------------------------------------------------------------------
// Causal depthwise conv1d (width 4) + bias + SiLU, float4 over channels.
// ---------------------------------------------------------------------------
__global__ __launch_bounds__(256) void conv_silu(
    const float* __restrict__ xz,   // [ML][4096], u half at [:,0:2048]
    const float* __restrict__ cw,   // [2048][4]
    const float* __restrict__ cb,   // [2048]
    float* __restrict__ u)          // [ML][2048]
{
    int idx = blockIdx.x * 256 + threadIdx.x;
    if (idx >= ML * (D_INNER / 4)) return;
    int d4  = idx & (D_INNER / 4 - 1);
    int row = idx >> 9;
    int l   = row & (SEQ - 1);

    const float* base = xz + (size_t)row * 4096 + d4 * 4;
    float xr[4][4];
    {
        float4 v = *reinterpret_cast<const float4*>(base);
        xr[0][0] = v.x; xr[0][1] = v.y; xr[0][2] = v.z; xr[0][3] = v.w;
    }
#pragma unroll
    for (int t = 1; t < 4; ++t) {
        float4 v = make_float4(0.f, 0.f, 0.f, 0.f);
        if (l >= t) v = *reinterpret_cast<const float4*>(base - (size_t)t * 4096);
        xr[t][0] = v.x; xr[t][1] = v.y; xr[t][2] = v.z; xr[t][3] = v.w;
    }
    float4 b4 = *reinterpret_cast<const float4*>(&cb[d4 * 4]);
    float bb[4] = {b4.x, b4.y, b4.z, b4.w};
    float out[4];
#pragma unroll
    for (int c = 0; c < 4; ++c) {
        float4 w = *reinterpret_cast<const float4*>(&cw[(d4 * 4 + c) * 4]);
        float s = bb[c];
        s = fmaf(w.w, xr[0][c], s);
        s = fmaf(w.z, xr[1][c], s);
        s = fmaf(w.y, xr[2][c], s);
        s = fmaf(w.x, xr[3][c], s);
        out[c] = s / (1.f + __expf(-s));
    }
    *reinterpret_cast<float4*>(&u[(size_t)row * 2048 + d4 * 4]) =
        make_float4(out[0], out[1], out[2], out[3]);
}

// ---------------------------------------------------------------------------
// x_proj split-K (f32): partial[s][m][c] over K-chunks of 256, then reduce.
// ---------------------------------------------------------------------------
__global__ __launch_bounds__(256) void xproj_partial(
    const float* __restrict__ u,    // [ML][2048]
    const float* __restrict__ W,    // [96][2048]
    float* __restrict__ part)       // [8][ML][96]
{
    __shared__ float Us[64][36];
    __shared__ float Ws[96][36];
    const int tid = threadIdx.x;
    const int tx = tid & 31;
    const int ty = tid >> 5;
    const int r0 = blockIdx.x * 64;
    const int kbase = blockIdx.y * 256;

    float acc[8][3] = {};

    for (int kc = kbase; kc < kbase + 256; kc += 32) {
#pragma unroll
        for (int i = 0; i < 2; ++i) {
            int f = tid + i * 256, row = f >> 3, kq = f & 7;
            *reinterpret_cast<float4*>(&Us[row][kq * 4]) =
                *reinterpret_cast<const float4*>(&u[(size_t)(r0 + row) * 2048 + kc + kq * 4]);
        }
#pragma unroll
        for (int i = 0; i < 3; ++i) {
            int f = tid + i * 256, row = f >> 3, kq = f & 7;
            *reinterpret_cast<float4*>(&Ws[row][kq * 4]) =
                *reinterpret_cast<const float4*>(&W[(size_t)row * 2048 + kc + kq * 4]);
        }
        __syncthreads();
#pragma unroll
        for (int k4 = 0; k4 < 32; k4 += 4) {
            float4 wv[3];
#pragma unroll
            for (int j = 0; j < 3; ++j)
                wv[j] = *reinterpret_cast<const float4*>(&Ws[tx + 32 * j][k4]);
#pragma unroll
            for (int i = 0; i < 8; ++i) {
                float4 uv = *reinterpret_cast<const float4*>(&Us[ty * 8 + i][k4]);
#pragma unroll
                for (int j = 0; j < 3; ++j) {
                    acc[i][j] = fmaf(uv.x, wv[j].x, acc[i][j]);
                    acc[i][j] = fmaf(uv.y, wv[j].y, acc[i][j]);
                    acc[i][j] = fmaf(uv.z, wv[j].z, acc[i][j]);
                    acc[i][j] = fmaf(uv.w, wv[j].w, acc[i][j]);
                }
            }
        }
        __syncthreads();
    }
#pragma unroll
    for (int i = 0; i < 8; ++i)
#pragma unroll
        for (int j = 0; j < 3; ++j)
            part[((size_t)blockIdx.y * ML + r0 + ty * 8 + i) * 96 + tx + 32 * j] = acc[i][j];
}

__global__ __launch_bounds__(256) void xproj_reduce(
    const float* __restrict__ part,  // [8][ML][96]
    float* __restrict__ xdbl)        // [ML][96]
{
    int i = blockIdx.x * 256 + threadIdx.x;
    if (i >= ML * 96 / 4) return;
    const float4* p4 = reinterpret_cast<const float4*>(part);
    float4 s = p4[i];
#pragma unroll
    for (int sgl = 1; sgl < 8; ++sgl) {
        float4 v = p4[(size_t)sgl * (ML * 96 / 4) + i];
        s.x += v.x; s.y += v.y; s.z += v.z; s.w += v.w;
    }
    reinterpret_cast<float4*>(xdbl)[i] = s;
}

// ---------------------------------------------------------------------------
// Selective scan: 256 threads = 16 channels x 16 states, fused gate epilogue.
// ---------------------------------------------------------------------------
#define CH 64

__global__ __launch_bounds__(256) void scan_kernel(
    const float* __restrict__ delta,   // [ML][2048]
    const float* __restrict__ u,       // [ML][2048]
    const float* __restrict__ xdbl,    // [ML][96]  (B 64:80, C 80:96)
    const float* __restrict__ xz,      // [ML][4096] (z at 2048+d)
    const float* __restrict__ A_log,   // [2048][16]
    const float* __restrict__ Dvec,    // [2048]
    float* __restrict__ yg)            // [ML][2048]
{
    __shared__ float sd[CH][16], su[CH][16], sB[CH][16],
                     sC[CH][16], sz[CH][16], sy[CH][16];
    const int tid = threadIdx.x;
    const int b   = blockIdx.x >> 7;
    const int d0  = (blockIdx.x & 127) * 16;
    const int dch = tid >> 4;
    const int n   = tid & 15;

    const float Aval = -expf(A_log[(d0 + dch) * 16 + n]);
    const float Dd   = Dvec[d0 + dch];
    float h = 0.f;

    for (int l0 = 0; l0 < SEQ; l0 += CH) {
#pragma unroll
        for (int i = 0; i < 4; ++i) {
            int lr  = (tid >> 4) + 16 * i;
            int row = b * SEQ + l0 + lr;
            int c   = tid & 15;
            sd[lr][c] = delta[(size_t)row * 2048 + d0 + c];
            su[lr][c] = u[(size_t)row * 2048 + d0 + c];
            sz[lr][c] = xz[(size_t)row * 4096 + 2048 + d0 + c];
            sB[lr][c] = xdbl[(size_t)row * 96 + 64 + c];
            sC[lr][c] = xdbl[(size_t)row * 96 + 80 + c];
        }
        __syncthreads();

        for (int l = 0; l < CH; ++l) {
            float dt = sd[l][dch];
            float uu = su[l][dch];
            float dA = __expf(dt * Aval);
            h = fmaf(dA, h, dt * uu * sB[l][n]);
            float p = h * sC[l][n];
            p += __shfl_xor(p, 1);
            p += __shfl_xor(p, 2);
            p += __shfl_xor(p, 4);
            p += __shfl_xor(p, 8);
            if (n == 0) {
                float zz = sz[l][dch];
                float g  = zz / (1.f + __expf(-zz));
                sy[l][dch] = (p + uu * Dd) * g;
            }
        }
        __syncthreads();

#pragma unroll
        for (int i = 0; i < 4; ++i) {
            int lr  = (tid >> 4) + 16 * i;
            int row = b * SEQ + l0 + lr;
            int c   = tid & 15;
            yg[(size_t)row * 2048 + d0 + c] = sy[lr][c];
        }
        __syncthreads();
    }
}

// ---------------------------------------------------------------------------
extern "C" void kernel_launch(void* const* d_in, const int* in_sizes, int n_in,
                              void* d_out, int out_size, void* d_ws, size_t ws_size,
                              hipStream_t stream)
{
    const float* x         = (const float*)d_in[0];  // [2,1024,1024]
    const float* in_proj_w = (const float*)d_in[1];  // [4096,1024]
    const float* conv_w    = (const float*)d_in[2];  // [2048,1,4]
    const float* conv_b    = (const float*)d_in[3];  // [2048]
    const float* x_proj_w  = (const float*)d_in[4];  // [96,2048]
    const float* dt_proj_w = (const float*)d_in[5];  // [2048,64]
    const float* dt_proj_b = (const float*)d_in[6];  // [2048]
    const float* A_log     = (const float*)d_in[7];  // [2048,16]
    const float* Dvec      = (const float*)d_in[8];  // [2048]
    const float* out_proj_w= (const float*)d_in[9];  // [1024,2048]
    float* out = (float*)d_out;                      // [2,1024,1024]

    float* ws    = (float*)d_ws;
    float* xz    = ws;                    // [ML][4096]  32 MB
    float* u     = ws + 8388608;          // [ML][2048]  16 MB
    float* xdbl  = ws + 12582912;         // [ML][96]    0.75 MB
    float* delta = ws + 12779520;         // [ML][2048]  16 MB (aliases part)
    float* part  = delta;                 // [8][ML][96] 6 MB, consumed before delta written
    float* yg    = ws + 16973824;         // [ML][2048]  16 MB

    // bf16 hi/lo region (24 MB), phase-aliased:
    ushort_t* bfb = (ushort_t*)(ws + 21168128);
    // phase 1 (in_proj):
    ushort_t* Xh  = bfb;                  // 2M elems
    ushort_t* Xl  = bfb + 2097152;
    ushort_t* Wih = bfb + 4194304;        // 4M
    ushort_t* Wil = bfb + 8388608;        // 4M
    // phase 2 (out_proj), aliases phase 1 (dead by then):
    ushort_t* Ygh = bfb;                  // 4M
    ushort_t* Ygl = bfb + 4194304;
    ushort_t* Woh = bfb + 8388608;        // 2M
    ushort_t* Wol = bfb + 10485760;

    // 1) split x and in_proj_w to tiled bf16 hi/lo
    split_bf16_tiled<<<dim3(1024), 256, 0, stream>>>(x, Xh, Xl, 1024, 5, ML * 1024 / 8);
    split_bf16_tiled<<<dim3(2048), 256, 0, stream>>>(in_proj_w, Wih, Wil, 1024, 5, 4096 * 1024 / 8);

    // 2) xz = x @ in_proj_w^T   (M=2048, N=4096, K=1024) — MFMA split
    gemm_mfma_split<4, false><<<dim3(32, 16), 256, 0, stream>>>(
        Xh, Xl, Wih, Wil, nullptr, xz, 4096, 1024);

    // 3) u = silu(causal_conv(xz[:, :2048]) + conv_b)
    conv_silu<<<dim3(ML * (D_INNER / 4) / 256), 256, 0, stream>>>(xz, conv_w, conv_b, u);

    // 4) x_dbl = u @ x_proj_w^T   (split-K f32 + reduce)
    xproj_partial<<<dim3(32, 8), 256, 0, stream>>>(u, x_proj_w, part);
    xproj_reduce<<<dim3((ML * 96 / 4 + 255) / 256), 256, 0, stream>>>(part, xdbl);

    // 5) delta = softplus(x_dbl[:, :64] @ dt_proj_w^T + dt_proj_b)  f32
    gemm_tn<128, 128, 8, 8, 1, true><<<dim3(16, 16), 256, 0, stream>>>(
        xdbl, 96, dt_proj_w, 64, dt_proj_b, delta, 2048, 64);

    // 6) selective scan + skip + gate -> yg (f32)
    scan_kernel<<<dim3(256), 256, 0, stream>>>(delta, u, xdbl, xz, A_log, Dvec, yg);

    // 7) split yg and out_proj_w
    split_bf16_tiled<<<dim3(2048), 256, 0, stream>>>(yg, Ygh, Ygl, 2048, 6, ML * 2048 / 8);
    split_bf16_tiled<<<dim3(1024), 256, 0, stream>>>(out_proj_w, Woh, Wol, 2048, 6, 1024 * 2048 / 8);

    // 8) out = yg @ out_proj_w^T + x   (M=2048, N=1024, K=2048) — MFMA split
    gemm_mfma_split<2, true><<<dim3(8, 32), 256, 0, stream>>>(
        Ygh, Ygl, Woh, Wol, x, out, 1024, 2048);
}

// Round 4
// 385.234 us; speedup vs baseline: 1.3979x; 1.3979x over previous
//
#include <hip/hip_runtime.h>
#include <hip/hip_bf16.h>
#include <math.h>

#define D_MODEL 1024
#define D_STATE 16
#define D_CONV  4
#define D_INNER 2048
#define DT_RANK 64
#define B_SZ    2
#define SEQ     1024
#define ML      (B_SZ * SEQ)   // 2048 rows (b*L)

typedef unsigned short ushort_t;
typedef __attribute__((ext_vector_type(8))) short s8v;
typedef __attribute__((ext_vector_type(4))) float f4v;

__device__ __forceinline__ float softplus_f(float v) {
    return (v > 20.f) ? v : log1pf(__expf(v));
}

// ---------------------------------------------------------------------------
// Split f32 -> (hi, lo) bf16 pair, written in GEMM-tiled layout:
// tile (rt, kt) of [128 rows][32 k] is 4096 contiguous elements at
// (rt*ktiles + kt)*4096, row-major [r][k]. One thread converts 8 k-elements.
// ---------------------------------------------------------------------------
__global__ __launch_bounds__(256) void split_bf16_tiled(
    const float* __restrict__ A, ushort_t* __restrict__ H, ushort_t* __restrict__ L,
    int Kd, int ktlog, int total)
{
    int t = blockIdx.x * 256 + threadIdx.x;
    if (t >= total) return;
    int kslot = t & 3;
    int r  = (t >> 2) & 127;
    int tl = t >> 9;
    int kt = tl & ((1 << ktlog) - 1);
    int rt = tl >> ktlog;
    int row = rt * 128 + r;
    int col = (kt << 5) + kslot * 8;

    const float* src = &A[(size_t)row * Kd + col];
    float4 v0 = *reinterpret_cast<const float4*>(src);
    float4 v1 = *reinterpret_cast<const float4*>(src + 4);
    float f[8] = {v0.x, v0.y, v0.z, v0.w, v1.x, v1.y, v1.z, v1.w};
    s8v hv, lv;
#pragma unroll
    for (int j = 0; j < 8; ++j) {
        unsigned int ub = __float_as_uint(f[j]);
        unsigned int hb = (ub + 0x7fffu + ((ub >> 16) & 1u)) >> 16;   // RNE to bf16
        float hf = __uint_as_float(hb << 16);
        float g  = f[j] - hf;                                         // exact
        unsigned int ug = __float_as_uint(g);
        unsigned int lb = (ug + 0x7fffu + ((ug >> 16) & 1u)) >> 16;
        hv[j] = (short)hb;
        lv[j] = (short)lb;
    }
    *reinterpret_cast<s8v*>(&H[(size_t)t * 8]) = hv;
    *reinterpret_cast<s8v*>(&L[(size_t)t * 8]) = lv;
}

// ---------------------------------------------------------------------------
// Split-bf16 MFMA GEMM (m97 structure): C[m,n] = sum_k A[m,k]*W[n,k] (+R)
// ---------------------------------------------------------------------------
template <int WTM, bool RES>
__global__ __launch_bounds__(256) void gemm_mfma_split(
    const ushort_t* __restrict__ Ah, const ushort_t* __restrict__ Al,
    const ushort_t* __restrict__ Bh, const ushort_t* __restrict__ Bl,
    const float* __restrict__ Rres,
    float* __restrict__ C, int ldc, int K)
{
    constexpr int BM  = WTM * 32;
    constexpr int CPW = BM / 64;            // A-chunks (of 16 rows) per wave
    __shared__ short AhL[BM * 32], AlL[BM * 32];
    __shared__ short BhL[128 * 32], BlL[128 * 32];

    const int tid = threadIdx.x;
    const int l = tid & 63;
    const int w = tid >> 6;
    const int m0 = blockIdx.y * BM;
    const int n0 = blockIdx.x * 128;
    const int wm = (w >> 1) * (WTM * 16);
    const int wn = (w & 1) * 64;

    const int ktiles = K >> 5;
    size_t abase = (size_t)(m0 >> 7) * ktiles * 4096 + (size_t)(m0 & 127) * 32;
    size_t bbase = (size_t)(n0 >> 7) * ktiles * 4096;

    f4v acc[WTM][4] = {};

    for (int kt = 0; kt < ktiles; ++kt) {
#pragma unroll
        for (int i = 0; i < CPW; ++i) {
            int ci = w * CPW + i;
            __builtin_amdgcn_global_load_lds(
                (const __attribute__((address_space(1))) unsigned int*)(Ah + abase + ci * 512 + l * 8),
                (__attribute__((address_space(3))) unsigned int*)&AhL[ci * 512], 16, 0, 0);
            __builtin_amdgcn_global_load_lds(
                (const __attribute__((address_space(1))) unsigned int*)(Al + abase + ci * 512 + l * 8),
                (__attribute__((address_space(3))) unsigned int*)&AlL[ci * 512], 16, 0, 0);
        }
#pragma unroll
        for (int i = 0; i < 2; ++i) {
            int ci = w * 2 + i;
            __builtin_amdgcn_global_load_lds(
                (const __attribute__((address_space(1))) unsigned int*)(Bh + bbase + ci * 512 + l * 8),
                (__attribute__((address_space(3))) unsigned int*)&BhL[ci * 512], 16, 0, 0);
            __builtin_amdgcn_global_load_lds(
                (const __attribute__((address_space(1))) unsigned int*)(Bl + bbase + ci * 512 + l * 8),
                (__attribute__((address_space(3))) unsigned int*)&BlL[ci * 512], 16, 0, 0);
        }
        asm volatile("s_waitcnt vmcnt(0)" ::: "memory");
        __syncthreads();

        s8v fah[WTM], fal[WTM], fbh[4], fbl[4];
        const int fo = (l & 15) * 32 + (l >> 4) * 8;
#pragma unroll
        for (int tr = 0; tr < WTM; ++tr) {
            fah[tr] = *reinterpret_cast<const s8v*>(&AhL[(wm + tr * 16) * 32 + fo]);
            fal[tr] = *reinterpret_cast<const s8v*>(&AlL[(wm + tr * 16) * 32 + fo]);
        }
#pragma unroll
        for (int tc = 0; tc < 4; ++tc) {
            fbh[tc] = *reinterpret_cast<const s8v*>(&BhL[(wn + tc * 16) * 32 + fo]);
            fbl[tc] = *reinterpret_cast<const s8v*>(&BlL[(wn + tc * 16) * 32 + fo]);
        }

#pragma unroll
        for (int tr = 0; tr < WTM; ++tr)
#pragma unroll
            for (int tc = 0; tc < 4; ++tc) {
                f4v c = acc[tr][tc];
                c = __builtin_amdgcn_mfma_f32_16x16x32_bf16(fah[tr], fbh[tc], c, 0, 0, 0);
                c = __builtin_amdgcn_mfma_f32_16x16x32_bf16(fah[tr], fbl[tc], c, 0, 0, 0);
                c = __builtin_amdgcn_mfma_f32_16x16x32_bf16(fal[tr], fbh[tc], c, 0, 0, 0);
                acc[tr][tc] = c;
            }
        __syncthreads();
        abase += 4096;
        bbase += 4096;
    }

    const int mb = m0 + wm + ((l >> 4) << 2);
    const int nb = n0 + wn + (l & 15);
#pragma unroll
    for (int tr = 0; tr < WTM; ++tr)
#pragma unroll
        for (int tc = 0; tc < 4; ++tc)
#pragma unroll
            for (int r = 0; r < 4; ++r) {
                int m = mb + tr * 16 + r;
                int n = nb + tc * 16;
                float v = acc[tr][tc][r];
                if (RES) v += Rres[(size_t)m * ldc + n];
                C[(size_t)m * ldc + n] = v;
            }
}

// ---------------------------------------------------------------------------
// f32 GEMM (dt_proj only): C = softplus(A@W^T + bias)
// ---------------------------------------------------------------------------
template <int BM, int BN, int TM, int TN, int ACT, bool BIAS>
__global__ __launch_bounds__(256) void gemm_tn(
    const float* __restrict__ A, int lda,
    const float* __restrict__ W, int ldw,
    const float* __restrict__ bias,
    float* __restrict__ C, int ldc,
    int K)
{
    constexpr int BK = 16;
    constexpr int LDA_S = BM + 4;
    constexpr int LDB_S = BN + 4;
    constexpr int RSUB = TM / 4;
    constexpr int CSUB = TN / 4;
    constexpr int NTX = BN / TN;
    constexpr int AF4 = BM * 4 / 256;
    constexpr int BF4 = BN * 4 / 256;
    static_assert((BM / TM) * (BN / TN) == 256, "256 threads");

    __shared__ float As[BK][LDA_S];
    __shared__ float Bs[BK][LDB_S];

    const int tid = threadIdx.x;
    const int tx = tid % NTX;
    const int ty = tid / NTX;
    const int m0 = blockIdx.y * BM;
    const int n0 = blockIdx.x * BN;

    float acc[TM][TN] = {};
    float4 pa[AF4], pb[BF4];

#pragma unroll
    for (int i = 0; i < AF4; ++i) {
        int f = tid + i * 256, row = f >> 2, kq = f & 3;
        pa[i] = *reinterpret_cast<const float4*>(&A[(size_t)(m0 + row) * lda + kq * 4]);
    }
#pragma unroll
    for (int i = 0; i < BF4; ++i) {
        int f = tid + i * 256, row = f >> 2, kq = f & 3;
        pb[i] = *reinterpret_cast<const float4*>(&W[(size_t)(n0 + row) * ldw + kq * 4]);
    }

    for (int k0 = 0; k0 < K; k0 += BK) {
#pragma unroll
        for (int i = 0; i < AF4; ++i) {
            int f = tid + i * 256, row = f >> 2, kq = f & 3;
            As[kq * 4 + 0][row] = pa[i].x; As[kq * 4 + 1][row] = pa[i].y;
            As[kq * 4 + 2][row] = pa[i].z; As[kq * 4 + 3][row] = pa[i].w;
        }
#pragma unroll
        for (int i = 0; i < BF4; ++i) {
            int f = tid + i * 256, row = f >> 2, kq = f & 3;
            Bs[kq * 4 + 0][row] = pb[i].x; Bs[kq * 4 + 1][row] = pb[i].y;
            Bs[kq * 4 + 2][row] = pb[i].z; Bs[kq * 4 + 3][row] = pb[i].w;
        }
        __syncthreads();

        if (k0 + BK < K) {
#pragma unroll
            for (int i = 0; i < AF4; ++i) {
                int f = tid + i * 256, row = f >> 2, kq = f & 3;
                pa[i] = *reinterpret_cast<const float4*>(&A[(size_t)(m0 + row) * lda + k0 + BK + kq * 4]);
            }
#pragma unroll
            for (int i = 0; i < BF4; ++i) {
                int f = tid + i * 256, row = f >> 2, kq = f & 3;
                pb[i] = *reinterpret_cast<const float4*>(&W[(size_t)(n0 + row) * ldw + k0 + BK + kq * 4]);
            }
        }

#pragma unroll
        for (int kk = 0; kk < BK; ++kk) {
            float a[TM], b[TN];
#pragma unroll
            for (int r = 0; r < RSUB; ++r) {
                float4 av = *reinterpret_cast<const float4*>(&As[kk][r * (BM / RSUB) + ty * 4]);
                a[r * 4 + 0] = av.x; a[r * 4 + 1] = av.y; a[r * 4 + 2] = av.z; a[r * 4 + 3] = av.w;
            }
#pragma unroll
            for (int c = 0; c < CSUB; ++c) {
                float4 bv = *reinterpret_cast<const float4*>(&Bs[kk][c * (BN / CSUB) + tx * 4]);
                b[c * 4 + 0] = bv.x; b[c * 4 + 1] = bv.y; b[c * 4 + 2] = bv.z; b[c * 4 + 3] = bv.w;
            }
#pragma unroll
            for (int i = 0; i < TM; ++i)
#pragma unroll
                for (int j = 0; j < TN; ++j)
                    acc[i][j] = fmaf(a[i], b[j], acc[i][j]);
        }
        __syncthreads();
    }

#pragma unroll
    for (int i = 0; i < TM; ++i) {
        int r = i >> 2, ii = i & 3;
        int m = m0 + r * (BM / RSUB) + ty * 4 + ii;
#pragma unroll
        for (int c = 0; c < CSUB; ++c) {
            int n = n0 + c * (BN / CSUB) + tx * 4;
            float v0 = acc[i][c * 4 + 0], v1 = acc[i][c * 4 + 1];
            float v2 = acc[i][c * 4 + 2], v3 = acc[i][c * 4 + 3];
            if (BIAS) {
                float4 b4 = *reinterpret_cast<const float4*>(&bias[n]);
                v0 += b4.x; v1 += b4.y; v2 += b4.z; v3 += b4.w;
            }
            if (ACT == 1) {
                v0 = softplus_f(v0); v1 = softplus_f(v1);
                v2 = softplus_f(v2); v3 = softplus_f(v3);
            }
            *reinterpret_cast<float4*>(&C[(size_t)m * ldc + n]) = make_float4(v0, v1, v2, v3);
        }
    }
}

// ---------------------------------------------------------------------------
// Causal depthwise conv1d (width 4) + bias + SiLU, float4 over channels.
// ---------------------------------------------------------------------------
__global__ __launch_bounds__(256) void conv_silu(
    const float* __restrict__ xz,
    const float* __restrict__ cw,
    const float* __restrict__ cb,
    float* __restrict__ u)
{
    int idx = blockIdx.x * 256 + threadIdx.x;
    if (idx >= ML * (D_INNER / 4)) return;
    int d4  = idx & (D_INNER / 4 - 1);
    int row = idx >> 9;
    int l   = row & (SEQ - 1);

    const float* base = xz + (size_t)row * 4096 + d4 * 4;
    float xr[4][4];
    {
        float4 v = *reinterpret_cast<const float4*>(base);
        xr[0][0] = v.x; xr[0][1] = v.y; xr[0][2] = v.z; xr[0][3] = v.w;
    }
#pragma unroll
    for (int t = 1; t < 4; ++t) {
        float4 v = make_float4(0.f, 0.f, 0.f, 0.f);
        if (l >= t) v = *reinterpret_cast<const float4*>(base - (size_t)t * 4096);
        xr[t][0] = v.x; xr[t][1] = v.y; xr[t][2] = v.z; xr[t][3] = v.w;
    }
    float4 b4 = *reinterpret_cast<const float4*>(&cb[d4 * 4]);
    float bb[4] = {b4.x, b4.y, b4.z, b4.w};
    float out[4];
#pragma unroll
    for (int c = 0; c < 4; ++c) {
        float4 w = *reinterpret_cast<const float4*>(&cw[(d4 * 4 + c) * 4]);
        float s = bb[c];
        s = fmaf(w.w, xr[0][c], s);
        s = fmaf(w.z, xr[1][c], s);
        s = fmaf(w.y, xr[2][c], s);
        s = fmaf(w.x, xr[3][c], s);
        out[c] = s / (1.f + __expf(-s));
    }
    *reinterpret_cast<float4*>(&u[(size_t)row * 2048 + d4 * 4]) =
        make_float4(out[0], out[1], out[2], out[3]);
}

// ---------------------------------------------------------------------------
// x_proj split-K (f32)
// ---------------------------------------------------------------------------
__global__ __launch_bounds__(256) void xproj_partial(
    const float* __restrict__ u,
    const float* __restrict__ W,
    float* __restrict__ part)
{
    __shared__ float Us[64][36];
    __shared__ float Ws[96][36];
    const int tid = threadIdx.x;
    const int tx = tid & 31;
    const int ty = tid >> 5;
    const int r0 = blockIdx.x * 64;
    const int kbase = blockIdx.y * 256;

    float acc[8][3] = {};

    for (int kc = kbase; kc < kbase + 256; kc += 32) {
#pragma unroll
        for (int i = 0; i < 2; ++i) {
            int f = tid + i * 256, row = f >> 3, kq = f & 7;
            *reinterpret_cast<float4*>(&Us[row][kq * 4]) =
                *reinterpret_cast<const float4*>(&u[(size_t)(r0 + row) * 2048 + kc + kq * 4]);
        }
#pragma unroll
        for (int i = 0; i < 3; ++i) {
            int f = tid + i * 256, row = f >> 3, kq = f & 7;
            *reinterpret_cast<float4*>(&Ws[row][kq * 4]) =
                *reinterpret_cast<const float4*>(&W[(size_t)row * 2048 + kc + kq * 4]);
        }
        __syncthreads();
#pragma unroll
        for (int k4 = 0; k4 < 32; k4 += 4) {
            float4 wv[3];
#pragma unroll
            for (int j = 0; j < 3; ++j)
                wv[j] = *reinterpret_cast<const float4*>(&Ws[tx + 32 * j][k4]);
#pragma unroll
            for (int i = 0; i < 8; ++i) {
                float4 uv = *reinterpret_cast<const float4*>(&Us[ty * 8 + i][k4]);
#pragma unroll
                for (int j = 0; j < 3; ++j) {
                    acc[i][j] = fmaf(uv.x, wv[j].x, acc[i][j]);
                    acc[i][j] = fmaf(uv.y, wv[j].y, acc[i][j]);
                    acc[i][j] = fmaf(uv.z, wv[j].z, acc[i][j]);
                    acc[i][j] = fmaf(uv.w, wv[j].w, acc[i][j]);
                }
            }
        }
        __syncthreads();
    }
#pragma unroll
    for (int i = 0; i < 8; ++i)
#pragma unroll
        for (int j = 0; j < 3; ++j)
            part[((size_t)blockIdx.y * ML + r0 + ty * 8 + i) * 96 + tx + 32 * j] = acc[i][j];
}

__global__ __launch_bounds__(256) void xproj_reduce(
    const float* __restrict__ part,
    float* __restrict__ xdbl)
{
    int i = blockIdx.x * 256 + threadIdx.x;
    if (i >= ML * 96 / 4) return;
    const float4* p4 = reinterpret_cast<const float4*>(part);
    float4 s = p4[i];
#pragma unroll
    for (int sgl = 1; sgl < 8; ++sgl) {
        float4 v = p4[(size_t)sgl * (ML * 96 / 4) + i];
        s.x += v.x; s.y += v.y; s.z += v.z; s.w += v.w;
    }
    reinterpret_cast<float4*>(xdbl)[i] = s;
}

// ---------------------------------------------------------------------------
// Selective scan v2. 256 threads = 16 channels x 16 states.
// LDS transposed [c][l] so each thread reads 4 steps per ds_read_b128.
// 16-state reduction via DPP row_shr adds (VALU pipe, batched x8 off the
// h-critical-path); sum lands in lane n==15 of each 16-lane row.
// u*D folded in via lane-15-only addend; silu(z) gate applied in the
// coalesced write-out phase reading z directly from global.
// ---------------------------------------------------------------------------
#define CH 64

__device__ __forceinline__ float dpp_add(float x, const int ctrl_unused) { return x; }

__global__ __launch_bounds__(256) void scan_kernel(
    const float* __restrict__ delta,   // [ML][2048]
    const float* __restrict__ u,       // [ML][2048]
    const float* __restrict__ xdbl,    // [ML][96]  (B 64:80, C 80:96)
    const float* __restrict__ xz,      // [ML][4096] (z at 2048+d)
    const float* __restrict__ A_log,   // [2048][16]
    const float* __restrict__ Dvec,    // [2048]
    float* __restrict__ yg)            // [ML][2048]
{
    __shared__ __align__(16) float sd[16][CH + 4], su[16][CH + 4],
                                   sB[16][CH + 4], sC[16][CH + 4];
    __shared__ __align__(16) float sy[CH][20];

    const int tid = threadIdx.x;
    const int b   = blockIdx.x >> 7;
    const int d0  = (blockIdx.x & 127) * 16;
    const int dch = tid >> 4;          // channel within group (0..15); 16-lane DPP row
    const int n   = tid & 15;          // state index

    // staging thread mapping (float4 over channels, all 64 rows in one pass)
    const int sc4 = (tid & 3) * 4;     // channel quad
    const int slr = tid >> 2;          // chunk-local row (0..63)

    const float Aval = -expf(A_log[(d0 + dch) * 16 + n]);
    const float Dsel = (n == 15) ? Dvec[d0 + dch] : 0.f;
    float h = 0.f;

    for (int l0 = 0; l0 < SEQ; l0 += CH) {
        // ---- stage chunk into LDS, transposed to [c][l] ----
        {
            int row = b * SEQ + l0 + slr;
            float4 dv = *reinterpret_cast<const float4*>(&delta[(size_t)row * 2048 + d0 + sc4]);
            float4 uv = *reinterpret_cast<const float4*>(&u[(size_t)row * 2048 + d0 + sc4]);
            float4 Bv = *reinterpret_cast<const float4*>(&xdbl[(size_t)row * 96 + 64 + sc4]);
            float4 Cv = *reinterpret_cast<const float4*>(&xdbl[(size_t)row * 96 + 80 + sc4]);
            sd[sc4 + 0][slr] = dv.x; sd[sc4 + 1][slr] = dv.y; sd[sc4 + 2][slr] = dv.z; sd[sc4 + 3][slr] = dv.w;
            su[sc4 + 0][slr] = uv.x; su[sc4 + 1][slr] = uv.y; su[sc4 + 2][slr] = uv.z; su[sc4 + 3][slr] = uv.w;
            sB[sc4 + 0][slr] = Bv.x; sB[sc4 + 1][slr] = Bv.y; sB[sc4 + 2][slr] = Bv.z; sB[sc4 + 3][slr] = Bv.w;
            sC[sc4 + 0][slr] = Cv.x; sC[sc4 + 1][slr] = Cv.y; sC[sc4 + 2][slr] = Cv.z; sC[sc4 + 3][slr] = Cv.w;
        }
        __syncthreads();

        // ---- sequential h-recurrence; reduces batched per 8 steps ----
        float pbuf[8];
#pragma unroll 2
        for (int l8 = 0; l8 < CH; l8 += 8) {
#pragma unroll
            for (int g = 0; g < 2; ++g) {
                const int l4 = l8 + g * 4;
                float4 d4 = *reinterpret_cast<const float4*>(&sd[dch][l4]);
                float4 u4 = *reinterpret_cast<const float4*>(&su[dch][l4]);
                float4 B4 = *reinterpret_cast<const float4*>(&sB[n][l4]);
                float4 C4 = *reinterpret_cast<const float4*>(&sC[n][l4]);
                float dts[4] = {d4.x, d4.y, d4.z, d4.w};
                float uus[4] = {u4.x, u4.y, u4.z, u4.w};
                float Bs4[4] = {B4.x, B4.y, B4.z, B4.w};
                float Cs4[4] = {C4.x, C4.y, C4.z, C4.w};
#pragma unroll
                for (int j = 0; j < 4; ++j) {
                    float dt = dts[j];
                    float dA = __expf(dt * Aval);
                    h = fmaf(dA, h, dt * uus[j] * Bs4[j]);
                    pbuf[g * 4 + j] = fmaf(uus[j], Dsel, h * Cs4[j]);  // lane15 adds u*D
                }
            }
            // batched 16-lane row reduction on VALU (DPP row_shr), independent chains
#pragma unroll
            for (int j = 0; j < 8; ++j) {
                float p = pbuf[j];
                p += __int_as_float(__builtin_amdgcn_update_dpp(0, __float_as_int(p), 0x111, 0xf, 0xf, true));
                p += __int_as_float(__builtin_amdgcn_update_dpp(0, __float_as_int(p), 0x112, 0xf, 0xf, true));
                p += __int_as_float(__builtin_amdgcn_update_dpp(0, __float_as_int(p), 0x114, 0xf, 0xf, true));
                p += __int_as_float(__builtin_amdgcn_update_dpp(0, __float_as_int(p), 0x118, 0xf, 0xf, true));
                pbuf[j] = p;   // lane 15 of each row holds the full sum
            }
            if (n == 15) {
#pragma unroll
                for (int j = 0; j < 8; ++j) sy[l8 + j][dch] = pbuf[j];
            }
        }
        __syncthreads();

        // ---- coalesced write-out with silu(z) gate (z straight from global) ----
        {
            int row = b * SEQ + l0 + slr;
            float4 ps = *reinterpret_cast<const float4*>(&sy[slr][sc4]);
            float4 zv = *reinterpret_cast<const float4*>(&xz[(size_t)row * 4096 + 2048 + d0 + sc4]);
            float o[4];
            float pp[4] = {ps.x, ps.y, ps.z, ps.w};
            float zzv[4] = {zv.x, zv.y, zv.z, zv.w};
#pragma unroll
            for (int q = 0; q < 4; ++q) {
                float zz = zzv[q];
                o[q] = pp[q] * (zz / (1.f + __expf(-zz)));
            }
            *reinterpret_cast<float4*>(&yg[(size_t)row * 2048 + d0 + sc4]) =
                make_float4(o[0], o[1], o[2], o[3]);
        }
        __syncthreads();
    }
}

// ---------------------------------------------------------------------------
extern "C" void kernel_launch(void* const* d_in, const int* in_sizes, int n_in,
                              void* d_out, int out_size, void* d_ws, size_t ws_size,
                              hipStream_t stream)
{
    const float* x         = (const float*)d_in[0];
    const float* in_proj_w = (const float*)d_in[1];
    const float* conv_w    = (const float*)d_in[2];
    const float* conv_b    = (const float*)d_in[3];
    const float* x_proj_w  = (const float*)d_in[4];
    const float* dt_proj_w = (const float*)d_in[5];
    const float* dt_proj_b = (const float*)d_in[6];
    const float* A_log     = (const float*)d_in[7];
    const float* Dvec      = (const float*)d_in[8];
    const float* out_proj_w= (const float*)d_in[9];
    float* out = (float*)d_out;

    float* ws    = (float*)d_ws;
    float* xz    = ws;                    // [ML][4096]  32 MB
    float* u     = ws + 8388608;          // [ML][2048]  16 MB
    float* xdbl  = ws + 12582912;         // [ML][96]    0.75 MB
    float* delta = ws + 12779520;         // [ML][2048]  16 MB (aliases part)
    float* part  = delta;                 // [8][ML][96] 6 MB, consumed before delta written
    float* yg    = ws + 16973824;         // [ML][2048]  16 MB

    ushort_t* bfb = (ushort_t*)(ws + 21168128);
    ushort_t* Xh  = bfb;
    ushort_t* Xl  = bfb + 2097152;
    ushort_t* Wih = bfb + 4194304;
    ushort_t* Wil = bfb + 8388608;
    ushort_t* Ygh = bfb;
    ushort_t* Ygl = bfb + 4194304;
    ushort_t* Woh = bfb + 8388608;
    ushort_t* Wol = bfb + 10485760;

    // 1) split x and in_proj_w to tiled bf16 hi/lo
    split_bf16_tiled<<<dim3(1024), 256, 0, stream>>>(x, Xh, Xl, 1024, 5, ML * 1024 / 8);
    split_bf16_tiled<<<dim3(2048), 256, 0, stream>>>(in_proj_w, Wih, Wil, 1024, 5, 4096 * 1024 / 8);

    // 2) xz = x @ in_proj_w^T   (M=2048, N=4096, K=1024) — MFMA split
    gemm_mfma_split<4, false><<<dim3(32, 16), 256, 0, stream>>>(
        Xh, Xl, Wih, Wil, nullptr, xz, 4096, 1024);

    // 3) u = silu(causal_conv(xz[:, :2048]) + conv_b)
    conv_silu<<<dim3(ML * (D_INNER / 4) / 256), 256, 0, stream>>>(xz, conv_w, conv_b, u);

    // 4) x_dbl = u @ x_proj_w^T   (split-K f32 + reduce)
    xproj_partial<<<dim3(32, 8), 256, 0, stream>>>(u, x_proj_w, part);
    xproj_reduce<<<dim3((ML * 96 / 4 + 255) / 256), 256, 0, stream>>>(part, xdbl);

    // 5) delta = softplus(x_dbl[:, :64] @ dt_proj_w^T + dt_proj_b)  f32
    gemm_tn<128, 128, 8, 8, 1, true><<<dim3(16, 16), 256, 0, stream>>>(
        xdbl, 96, dt_proj_w, 64, dt_proj_b, delta, 2048, 64);

    // 6) selective scan + skip + gate -> yg (scan v2: b128 LDS + DPP reduce)
    scan_kernel<<<dim3(256), 256, 0, stream>>>(delta, u, xdbl, xz, A_log, Dvec, yg);

    // 7) split yg and out_proj_w
    split_bf16_tiled<<<dim3(2048), 256, 0, stream>>>(yg, Ygh, Ygl, 2048, 6, ML * 2048 / 8);
    split_bf16_tiled<<<dim3(1024), 256, 0, stream>>>(out_proj_w, Woh, Wol, 2048, 6, 1024 * 2048 / 8);

    // 8) out = yg @ out_proj_w^T + x   (M=2048, N=1024, K=2048) — MFMA split
    gemm_mfma_split<2, true><<<dim3(8, 32), 256, 0, stream>>>(
        Ygh, Ygl, Woh, Wol, x, out, 1024, 2048);
}

// Round 5
// 351.215 us; speedup vs baseline: 1.5333x; 1.0969x over previous
//
#include <hip/hip_runtime.h>
#include <hip/hip_bf16.h>
#include <math.h>

#define D_MODEL 1024
#define D_STATE 16
#define D_CONV  4
#define D_INNER 2048
#define DT_RANK 64
#define B_SZ    2
#define SEQ     1024
#define ML      (B_SZ * SEQ)   // 2048 rows (b*L)

typedef unsigned short ushort_t;
typedef __attribute__((ext_vector_type(8))) short s8v;
typedef __attribute__((ext_vector_type(4))) float f4v;

__device__ __forceinline__ float softplus_f(float v) {
    return (v > 20.f) ? v : log1pf(__expf(v));
}

// ---------------------------------------------------------------------------
// Split f32 -> (hi, lo) bf16 pair, written in GEMM-tiled layout:
// tile (rt, kt) of [128 rows][32 k] is 4096 contiguous elements at
// (rt*ktiles + kt)*4096, row-major [r][k]. One thread converts 8 k-elements.
// ---------------------------------------------------------------------------
__global__ __launch_bounds__(256) void split_bf16_tiled(
    const float* __restrict__ A, ushort_t* __restrict__ H, ushort_t* __restrict__ L,
    int Kd, int ktlog, int total)
{
    int t = blockIdx.x * 256 + threadIdx.x;
    if (t >= total) return;
    int kslot = t & 3;
    int r  = (t >> 2) & 127;
    int tl = t >> 9;
    int kt = tl & ((1 << ktlog) - 1);
    int rt = tl >> ktlog;
    int row = rt * 128 + r;
    int col = (kt << 5) + kslot * 8;

    const float* src = &A[(size_t)row * Kd + col];
    float4 v0 = *reinterpret_cast<const float4*>(src);
    float4 v1 = *reinterpret_cast<const float4*>(src + 4);
    float f[8] = {v0.x, v0.y, v0.z, v0.w, v1.x, v1.y, v1.z, v1.w};
    s8v hv, lv;
#pragma unroll
    for (int j = 0; j < 8; ++j) {
        unsigned int ub = __float_as_uint(f[j]);
        unsigned int hb = (ub + 0x7fffu + ((ub >> 16) & 1u)) >> 16;   // RNE to bf16
        float hf = __uint_as_float(hb << 16);
        float g  = f[j] - hf;                                         // exact
        unsigned int ug = __float_as_uint(g);
        unsigned int lb = (ug + 0x7fffu + ((ug >> 16) & 1u)) >> 16;
        hv[j] = (short)hb;
        lv[j] = (short)lb;
    }
    *reinterpret_cast<s8v*>(&H[(size_t)t * 8]) = hv;
    *reinterpret_cast<s8v*>(&L[(size_t)t * 8]) = lv;
}

// ---------------------------------------------------------------------------
// Split-bf16 MFMA GEMM (m97 structure): C[m,n] = sum_k A[m,k]*W[n,k] (+R)
// ---------------------------------------------------------------------------
template <int WTM, bool RES>
__global__ __launch_bounds__(256) void gemm_mfma_split(
    const ushort_t* __restrict__ Ah, const ushort_t* __restrict__ Al,
    const ushort_t* __restrict__ Bh, const ushort_t* __restrict__ Bl,
    const float* __restrict__ Rres,
    float* __restrict__ C, int ldc, int K)
{
    constexpr int BM  = WTM * 32;
    constexpr int CPW = BM / 64;            // A-chunks (of 16 rows) per wave
    __shared__ short AhL[BM * 32], AlL[BM * 32];
    __shared__ short BhL[128 * 32], BlL[128 * 32];

    const int tid = threadIdx.x;
    const int l = tid & 63;
    const int w = tid >> 6;
    const int m0 = blockIdx.y * BM;
    const int n0 = blockIdx.x * 128;
    const int wm = (w >> 1) * (WTM * 16);
    const int wn = (w & 1) * 64;

    const int ktiles = K >> 5;
    size_t abase = (size_t)(m0 >> 7) * ktiles * 4096 + (size_t)(m0 & 127) * 32;
    size_t bbase = (size_t)(n0 >> 7) * ktiles * 4096;

    f4v acc[WTM][4] = {};

    for (int kt = 0; kt < ktiles; ++kt) {
#pragma unroll
        for (int i = 0; i < CPW; ++i) {
            int ci = w * CPW + i;
            __builtin_amdgcn_global_load_lds(
                (const __attribute__((address_space(1))) unsigned int*)(Ah + abase + ci * 512 + l * 8),
                (__attribute__((address_space(3))) unsigned int*)&AhL[ci * 512], 16, 0, 0);
            __builtin_amdgcn_global_load_lds(
                (const __attribute__((address_space(1))) unsigned int*)(Al + abase + ci * 512 + l * 8),
                (__attribute__((address_space(3))) unsigned int*)&AlL[ci * 512], 16, 0, 0);
        }
#pragma unroll
        for (int i = 0; i < 2; ++i) {
            int ci = w * 2 + i;
            __builtin_amdgcn_global_load_lds(
                (const __attribute__((address_space(1))) unsigned int*)(Bh + bbase + ci * 512 + l * 8),
                (__attribute__((address_space(3))) unsigned int*)&BhL[ci * 512], 16, 0, 0);
            __builtin_amdgcn_global_load_lds(
                (const __attribute__((address_space(1))) unsigned int*)(Bl + bbase + ci * 512 + l * 8),
                (__attribute__((address_space(3))) unsigned int*)&BlL[ci * 512], 16, 0, 0);
        }
        asm volatile("s_waitcnt vmcnt(0)" ::: "memory");
        __syncthreads();

        s8v fah[WTM], fal[WTM], fbh[4], fbl[4];
        const int fo = (l & 15) * 32 + (l >> 4) * 8;
#pragma unroll
        for (int tr = 0; tr < WTM; ++tr) {
            fah[tr] = *reinterpret_cast<const s8v*>(&AhL[(wm + tr * 16) * 32 + fo]);
            fal[tr] = *reinterpret_cast<const s8v*>(&AlL[(wm + tr * 16) * 32 + fo]);
        }
#pragma unroll
        for (int tc = 0; tc < 4; ++tc) {
            fbh[tc] = *reinterpret_cast<const s8v*>(&BhL[(wn + tc * 16) * 32 + fo]);
            fbl[tc] = *reinterpret_cast<const s8v*>(&BlL[(wn + tc * 16) * 32 + fo]);
        }

#pragma unroll
        for (int tr = 0; tr < WTM; ++tr)
#pragma unroll
            for (int tc = 0; tc < 4; ++tc) {
                f4v c = acc[tr][tc];
                c = __builtin_amdgcn_mfma_f32_16x16x32_bf16(fah[tr], fbh[tc], c, 0, 0, 0);
                c = __builtin_amdgcn_mfma_f32_16x16x32_bf16(fah[tr], fbl[tc], c, 0, 0, 0);
                c = __builtin_amdgcn_mfma_f32_16x16x32_bf16(fal[tr], fbh[tc], c, 0, 0, 0);
                acc[tr][tc] = c;
            }
        __syncthreads();
        abase += 4096;
        bbase += 4096;
    }

    const int mb = m0 + wm + ((l >> 4) << 2);
    const int nb = n0 + wn + (l & 15);
#pragma unroll
    for (int tr = 0; tr < WTM; ++tr)
#pragma unroll
        for (int tc = 0; tc < 4; ++tc)
#pragma unroll
            for (int r = 0; r < 4; ++r) {
                int m = mb + tr * 16 + r;
                int n = nb + tc * 16;
                float v = acc[tr][tc][r];
                if (RES) v += Rres[(size_t)m * ldc + n];
                C[(size_t)m * ldc + n] = v;
            }
}

// ---------------------------------------------------------------------------
// Causal depthwise conv1d (width 4) + bias + SiLU, float4 over channels.
// ---------------------------------------------------------------------------
__global__ __launch_bounds__(256) void conv_silu(
    const float* __restrict__ xz,
    const float* __restrict__ cw,
    const float* __restrict__ cb,
    float* __restrict__ u)
{
    int idx = blockIdx.x * 256 + threadIdx.x;
    if (idx >= ML * (D_INNER / 4)) return;
    int d4  = idx & (D_INNER / 4 - 1);
    int row = idx >> 9;
    int l   = row & (SEQ - 1);

    const float* base = xz + (size_t)row * 4096 + d4 * 4;
    float xr[4][4];
    {
        float4 v = *reinterpret_cast<const float4*>(base);
        xr[0][0] = v.x; xr[0][1] = v.y; xr[0][2] = v.z; xr[0][3] = v.w;
    }
#pragma unroll
    for (int t = 1; t < 4; ++t) {
        float4 v = make_float4(0.f, 0.f, 0.f, 0.f);
        if (l >= t) v = *reinterpret_cast<const float4*>(base - (size_t)t * 4096);
        xr[t][0] = v.x; xr[t][1] = v.y; xr[t][2] = v.z; xr[t][3] = v.w;
    }
    float4 b4 = *reinterpret_cast<const float4*>(&cb[d4 * 4]);
    float bb[4] = {b4.x, b4.y, b4.z, b4.w};
    float out[4];
#pragma unroll
    for (int c = 0; c < 4; ++c) {
        float4 w = *reinterpret_cast<const float4*>(&cw[(d4 * 4 + c) * 4]);
        float s = bb[c];
        s = fmaf(w.w, xr[0][c], s);
        s = fmaf(w.z, xr[1][c], s);
        s = fmaf(w.y, xr[2][c], s);
        s = fmaf(w.x, xr[3][c], s);
        out[c] = s / (1.f + __expf(-s));
    }
    *reinterpret_cast<float4*>(&u[(size_t)row * 2048 + d4 * 4]) =
        make_float4(out[0], out[1], out[2], out[3]);
}

// ---------------------------------------------------------------------------
// x_proj split-K (f32)
// ---------------------------------------------------------------------------
__global__ __launch_bounds__(256) void xproj_partial(
    const float* __restrict__ u,
    const float* __restrict__ W,
    float* __restrict__ part)
{
    __shared__ float Us[64][36];
    __shared__ float Ws[96][36];
    const int tid = threadIdx.x;
    const int tx = tid & 31;
    const int ty = tid >> 5;
    const int r0 = blockIdx.x * 64;
    const int kbase = blockIdx.y * 256;

    float acc[8][3] = {};

    for (int kc = kbase; kc < kbase + 256; kc += 32) {
#pragma unroll
        for (int i = 0; i < 2; ++i) {
            int f = tid + i * 256, row = f >> 3, kq = f & 7;
            *reinterpret_cast<float4*>(&Us[row][kq * 4]) =
                *reinterpret_cast<const float4*>(&u[(size_t)(r0 + row) * 2048 + kc + kq * 4]);
        }
#pragma unroll
        for (int i = 0; i < 3; ++i) {
            int f = tid + i * 256, row = f >> 3, kq = f & 7;
            *reinterpret_cast<float4*>(&Ws[row][kq * 4]) =
                *reinterpret_cast<const float4*>(&W[(size_t)row * 2048 + kc + kq * 4]);
        }
        __syncthreads();
#pragma unroll
        for (int k4 = 0; k4 < 32; k4 += 4) {
            float4 wv[3];
#pragma unroll
            for (int j = 0; j < 3; ++j)
                wv[j] = *reinterpret_cast<const float4*>(&Ws[tx + 32 * j][k4]);
#pragma unroll
            for (int i = 0; i < 8; ++i) {
                float4 uv = *reinterpret_cast<const float4*>(&Us[ty * 8 + i][k4]);
#pragma unroll
                for (int j = 0; j < 3; ++j) {
                    acc[i][j] = fmaf(uv.x, wv[j].x, acc[i][j]);
                    acc[i][j] = fmaf(uv.y, wv[j].y, acc[i][j]);
                    acc[i][j] = fmaf(uv.z, wv[j].z, acc[i][j]);
                    acc[i][j] = fmaf(uv.w, wv[j].w, acc[i][j]);
                }
            }
        }
        __syncthreads();
    }
#pragma unroll
    for (int i = 0; i < 8; ++i)
#pragma unroll
        for (int j = 0; j < 3; ++j)
            part[((size_t)blockIdx.y * ML + r0 + ty * 8 + i) * 96 + tx + 32 * j] = acc[i][j];
}

__global__ __launch_bounds__(256) void xproj_reduce(
    const float* __restrict__ part,
    float* __restrict__ xdbl)
{
    int i = blockIdx.x * 256 + threadIdx.x;
    if (i >= ML * 96 / 4) return;
    const float4* p4 = reinterpret_cast<const float4*>(part);
    float4 s = p4[i];
#pragma unroll
    for (int sgl = 1; sgl < 8; ++sgl) {
        float4 v = p4[(size_t)sgl * (ML * 96 / 4) + i];
        s.x += v.x; s.y += v.y; s.z += v.z; s.w += v.w;
    }
    reinterpret_cast<float4*>(xdbl)[i] = s;
}

// ---------------------------------------------------------------------------
// Selective scan v3: dt_proj + softplus FUSED.
// Block = 256 threads = 16 channels x 16 states, one batch b.
// Per 64-step chunk: stage dt-rows/u/B/C -> LDS; compute
// delta[ch][l] = softplus(dot64(dt_row[l], dtw[ch]) + db[ch]) in LDS;
// then h-recurrence with DPP row reduction (v2 structure); gated write-out.
// ---------------------------------------------------------------------------
#define CH 64

__global__ __launch_bounds__(256) void scan_kernel(
    const float* __restrict__ u,       // [ML][2048]
    const float* __restrict__ xdbl,    // [ML][96]  (dt 0:64, B 64:80, C 80:96)
    const float* __restrict__ xz,      // [ML][4096] (z at 2048+d)
    const float* __restrict__ A_log,   // [2048][16]
    const float* __restrict__ Dvec,    // [2048]
    const float* __restrict__ dtw,     // [2048][64]
    const float* __restrict__ dtb,     // [2048]
    float* __restrict__ yg)            // [ML][2048]
{
    __shared__ __align__(16) float sdt[CH][68];                     // dt rows [l][k]
    __shared__ __align__(16) float sdel[16][CH + 4], su16[16][CH + 4],
                                   sB[16][CH + 4], sC[16][CH + 4];  // [ch|n][l]
    __shared__ __align__(16) float dtw_s[16][68];                   // [ch][k]
    __shared__ float db_s[16];
    __shared__ __align__(16) float sy[CH][20];

    const int tid = threadIdx.x;
    const int b   = blockIdx.x >> 7;
    const int d0  = (blockIdx.x & 127) * 16;
    const int dch = tid >> 4;          // channel (0..15); 16-lane DPP row
    const int n   = tid & 15;          // state index

    const int sc4 = (tid & 3) * 4;     // channel quad for staging / delta / write-out
    const int slr = tid >> 2;          // chunk-local row (0..63)

    // one-time: dtw tile (16x64) + bias to LDS
    {
        int r = tid >> 4, c4 = (tid & 15) * 4;
        *reinterpret_cast<float4*>(&dtw_s[r][c4]) =
            *reinterpret_cast<const float4*>(&dtw[(size_t)(d0 + r) * 64 + c4]);
        if (tid < 16) db_s[tid] = dtb[d0 + tid];
    }
    const float Aval = -expf(A_log[(d0 + dch) * 16 + n]);
    const float Dsel = (n == 15) ? Dvec[d0 + dch] : 0.f;
    float h = 0.f;
    __syncthreads();

    for (int l0 = 0; l0 < SEQ; l0 += CH) {
        // ---- stage chunk into LDS ----
        {
#pragma unroll
            for (int i = 0; i < 4; ++i) {              // dt rows: [l][k] layout
                int idx = tid + i * 256;
                int rr = idx >> 4, c4 = (idx & 15) * 4;
                *reinterpret_cast<float4*>(&sdt[rr][c4]) =
                    *reinterpret_cast<const float4*>(&xdbl[(size_t)(b * SEQ + l0 + rr) * 96 + c4]);
            }
            int row = b * SEQ + l0 + slr;
            float4 uv = *reinterpret_cast<const float4*>(&u[(size_t)row * 2048 + d0 + sc4]);
            float4 Bv = *reinterpret_cast<const float4*>(&xdbl[(size_t)row * 96 + 64 + sc4]);
            float4 Cv = *reinterpret_cast<const float4*>(&xdbl[(size_t)row * 96 + 80 + sc4]);
            su16[sc4 + 0][slr] = uv.x; su16[sc4 + 1][slr] = uv.y;
            su16[sc4 + 2][slr] = uv.z; su16[sc4 + 3][slr] = uv.w;
            sB[sc4 + 0][slr] = Bv.x; sB[sc4 + 1][slr] = Bv.y;
            sB[sc4 + 2][slr] = Bv.z; sB[sc4 + 3][slr] = Bv.w;
            sC[sc4 + 0][slr] = Cv.x; sC[sc4 + 1][slr] = Cv.y;
            sC[sc4 + 2][slr] = Cv.z; sC[sc4 + 3][slr] = Cv.w;
        }
        __syncthreads();

        // ---- fused dt_proj: delta[ch][l] for this chunk ----
        {
            float4 s0 = make_float4(0.f, 0.f, 0.f, 0.f), s1 = s0, s2 = s0, s3 = s0;
#pragma unroll
            for (int k4 = 0; k4 < 64; k4 += 4) {
                float4 dv = *reinterpret_cast<const float4*>(&sdt[slr][k4]);
                float4 w0 = *reinterpret_cast<const float4*>(&dtw_s[sc4 + 0][k4]);
                float4 w1 = *reinterpret_cast<const float4*>(&dtw_s[sc4 + 1][k4]);
                float4 w2 = *reinterpret_cast<const float4*>(&dtw_s[sc4 + 2][k4]);
                float4 w3 = *reinterpret_cast<const float4*>(&dtw_s[sc4 + 3][k4]);
                s0.x = fmaf(dv.x, w0.x, s0.x); s0.y = fmaf(dv.y, w0.y, s0.y);
                s0.z = fmaf(dv.z, w0.z, s0.z); s0.w = fmaf(dv.w, w0.w, s0.w);
                s1.x = fmaf(dv.x, w1.x, s1.x); s1.y = fmaf(dv.y, w1.y, s1.y);
                s1.z = fmaf(dv.z, w1.z, s1.z); s1.w = fmaf(dv.w, w1.w, s1.w);
                s2.x = fmaf(dv.x, w2.x, s2.x); s2.y = fmaf(dv.y, w2.y, s2.y);
                s2.z = fmaf(dv.z, w2.z, s2.z); s2.w = fmaf(dv.w, w2.w, s2.w);
                s3.x = fmaf(dv.x, w3.x, s3.x); s3.y = fmaf(dv.y, w3.y, s3.y);
                s3.z = fmaf(dv.z, w3.z, s3.z); s3.w = fmaf(dv.w, w3.w, s3.w);
            }
            sdel[sc4 + 0][slr] = softplus_f((s0.x + s0.y) + (s0.z + s0.w) + db_s[sc4 + 0]);
            sdel[sc4 + 1][slr] = softplus_f((s1.x + s1.y) + (s1.z + s1.w) + db_s[sc4 + 1]);
            sdel[sc4 + 2][slr] = softplus_f((s2.x + s2.y) + (s2.z + s2.w) + db_s[sc4 + 2]);
            sdel[sc4 + 3][slr] = softplus_f((s3.x + s3.y) + (s3.z + s3.w) + db_s[sc4 + 3]);
        }
        __syncthreads();

        // ---- sequential h-recurrence; reduces batched per 8 steps ----
        float pbuf[8];
#pragma unroll 2
        for (int l8 = 0; l8 < CH; l8 += 8) {
#pragma unroll
            for (int g = 0; g < 2; ++g) {
                const int l4 = l8 + g * 4;
                float4 d4 = *reinterpret_cast<const float4*>(&sdel[dch][l4]);
                float4 u4 = *reinterpret_cast<const float4*>(&su16[dch][l4]);
                float4 B4 = *reinterpret_cast<const float4*>(&sB[n][l4]);
                float4 C4 = *reinterpret_cast<const float4*>(&sC[n][l4]);
                float dts[4] = {d4.x, d4.y, d4.z, d4.w};
                float uus[4] = {u4.x, u4.y, u4.z, u4.w};
                float Bs4[4] = {B4.x, B4.y, B4.z, B4.w};
                float Cs4[4] = {C4.x, C4.y, C4.z, C4.w};
#pragma unroll
                for (int j = 0; j < 4; ++j) {
                    float dt = dts[j];
                    float dA = __expf(dt * Aval);
                    h = fmaf(dA, h, dt * uus[j] * Bs4[j]);
                    pbuf[g * 4 + j] = fmaf(uus[j], Dsel, h * Cs4[j]);  // lane15 adds u*D
                }
            }
#pragma unroll
            for (int j = 0; j < 8; ++j) {
                float p = pbuf[j];
                p += __int_as_float(__builtin_amdgcn_update_dpp(0, __float_as_int(p), 0x111, 0xf, 0xf, true));
                p += __int_as_float(__builtin_amdgcn_update_dpp(0, __float_as_int(p), 0x112, 0xf, 0xf, true));
                p += __int_as_float(__builtin_amdgcn_update_dpp(0, __float_as_int(p), 0x114, 0xf, 0xf, true));
                p += __int_as_float(__builtin_amdgcn_update_dpp(0, __float_as_int(p), 0x118, 0xf, 0xf, true));
                pbuf[j] = p;   // lane 15 of each row holds the full sum
            }
            if (n == 15) {
#pragma unroll
                for (int j = 0; j < 8; ++j) sy[l8 + j][dch] = pbuf[j];
            }
        }
        __syncthreads();

        // ---- coalesced write-out with silu(z) gate ----
        {
            int row = b * SEQ + l0 + slr;
            float4 ps = *reinterpret_cast<const float4*>(&sy[slr][sc4]);
            float4 zv = *reinterpret_cast<const float4*>(&xz[(size_t)row * 4096 + 2048 + d0 + sc4]);
            float o[4];
            float pp[4] = {ps.x, ps.y, ps.z, ps.w};
            float zzv[4] = {zv.x, zv.y, zv.z, zv.w};
#pragma unroll
            for (int q = 0; q < 4; ++q) {
                float zz = zzv[q];
                o[q] = pp[q] * (zz / (1.f + __expf(-zz)));
            }
            *reinterpret_cast<float4*>(&yg[(size_t)row * 2048 + d0 + sc4]) =
                make_float4(o[0], o[1], o[2], o[3]);
        }
        __syncthreads();
    }
}

// ---------------------------------------------------------------------------
extern "C" void kernel_launch(void* const* d_in, const int* in_sizes, int n_in,
                              void* d_out, int out_size, void* d_ws, size_t ws_size,
                              hipStream_t stream)
{
    const float* x         = (const float*)d_in[0];
    const float* in_proj_w = (const float*)d_in[1];
    const float* conv_w    = (const float*)d_in[2];
    const float* conv_b    = (const float*)d_in[3];
    const float* x_proj_w  = (const float*)d_in[4];
    const float* dt_proj_w = (const float*)d_in[5];
    const float* dt_proj_b = (const float*)d_in[6];
    const float* A_log     = (const float*)d_in[7];
    const float* Dvec      = (const float*)d_in[8];
    const float* out_proj_w= (const float*)d_in[9];
    float* out = (float*)d_out;

    float* ws    = (float*)d_ws;
    float* xz    = ws;                    // [ML][4096]  32 MB
    float* u     = ws + 8388608;          // [ML][2048]  16 MB
    float* xdbl  = ws + 12582912;         // [ML][96]    0.75 MB
    float* part  = ws + 12779520;         // [8][ML][96] 6 MB
    float* yg    = ws + 16973824;         // [ML][2048]  16 MB

    ushort_t* bfb = (ushort_t*)(ws + 21168128);
    ushort_t* Xh  = bfb;
    ushort_t* Xl  = bfb + 2097152;
    ushort_t* Wih = bfb + 4194304;
    ushort_t* Wil = bfb + 8388608;
    ushort_t* Ygh = bfb;
    ushort_t* Ygl = bfb + 4194304;
    ushort_t* Woh = bfb + 8388608;
    ushort_t* Wol = bfb + 10485760;

    // 1) split x and in_proj_w to tiled bf16 hi/lo
    split_bf16_tiled<<<dim3(1024), 256, 0, stream>>>(x, Xh, Xl, 1024, 5, ML * 1024 / 8);
    split_bf16_tiled<<<dim3(2048), 256, 0, stream>>>(in_proj_w, Wih, Wil, 1024, 5, 4096 * 1024 / 8);

    // 2) xz = x @ in_proj_w^T   (M=2048, N=4096, K=1024) — MFMA split
    gemm_mfma_split<4, false><<<dim3(32, 16), 256, 0, stream>>>(
        Xh, Xl, Wih, Wil, nullptr, xz, 4096, 1024);

    // 3) u = silu(causal_conv(xz[:, :2048]) + conv_b)
    conv_silu<<<dim3(ML * (D_INNER / 4) / 256), 256, 0, stream>>>(xz, conv_w, conv_b, u);

    // 4) x_dbl = u @ x_proj_w^T   (split-K f32 + reduce)
    xproj_partial<<<dim3(32, 8), 256, 0, stream>>>(u, x_proj_w, part);
    xproj_reduce<<<dim3((ML * 96 / 4 + 255) / 256), 256, 0, stream>>>(part, xdbl);

    // 5) scan with FUSED dt_proj+softplus, skip + gate -> yg
    scan_kernel<<<dim3(256), 256, 0, stream>>>(
        u, xdbl, xz, A_log, Dvec, dt_proj_w, dt_proj_b, yg);

    // 6) split yg and out_proj_w
    split_bf16_tiled<<<dim3(2048), 256, 0, stream>>>(yg, Ygh, Ygl, 2048, 6, ML * 2048 / 8);
    split_bf16_tiled<<<dim3(1024), 256, 0, stream>>>(out_proj_w, Woh, Wol, 2048, 6, 1024 * 2048 / 8);

    // 7) out = yg @ out_proj_w^T + x   (M=2048, N=1024, K=2048) — MFMA split
    gemm_mfma_split<2, true><<<dim3(8, 32), 256, 0, stream>>>(
        Ygh, Ygl, Woh, Wol, x, out, 1024, 2048);
}